// Round 9
// baseline (905.548 us; speedup 1.0000x reference)
//
#include <hip/hip_runtime.h>

#define N_NODES 100000
#define N_EDGES 1600000
#define N_GRAPHS 512
#define D_IN 128
#define D_H 64
#define D_OUT 32
#define N_CONV 4
#define BN_EPS 1e-5f
#define NSLOT 32

#define NB 512        // buckets
#define NPB 196       // nodes per bucket
#define NBUSED 511
#define CHUNK 8192    // edges per binned_scatter block
#define MAXE 4096     // max edges per bucket (mean 3136)

typedef unsigned short ushort_t;
typedef unsigned int uint_t;
typedef __attribute__((ext_vector_type(8))) short bf16x8;
typedef __attribute__((ext_vector_type(4))) float f32x4;
union U4B8 { uint4 u; bf16x8 v; };

__device__ inline float b2f(ushort_t u) {
    union { uint_t i; float f; } c; c.i = ((uint_t)u) << 16; return c.f;
}
__device__ inline ushort_t f2b(float f) {
    union { uint_t i; float f; } c; c.f = f;
    uint_t r = (c.i + 0x7fffu + ((c.i >> 16) & 1u)) >> 16;
    return (ushort_t)r;
}
__device__ inline float blo(uint_t v) { return b2f((ushort_t)(v & 0xffffu)); }
__device__ inline float bhi(uint_t v) { return b2f((ushort_t)(v >> 16)); }

// ---------------- utility: zero a region ------------------------------------
__global__ __launch_bounds__(256) void zero_kernel(int* __restrict__ p, int nwords) {
    int i = blockIdx.x * 256 + threadIdx.x;
    if (i < nwords) p[i] = 0;
}

// ---------------- CSR build: bucket histogram -------------------------------
__global__ __launch_bounds__(256) void bucket_count(const int* __restrict__ dst,
                                                    int* __restrict__ bucketCnt) {
    __shared__ int l[NB];
    int t = threadIdx.x;
    for (int i = t; i < NB; i += 256) l[i] = 0;
    __syncthreads();
    long base = (long)blockIdx.x * 4096;
    for (int i = t; i < 4096; i += 256) {
        long e = base + i;
        if (e < N_EDGES) atomicAdd(&l[(unsigned)dst[e] / NPB], 1);
    }
    __syncthreads();
    for (int i = t; i < NB; i += 256) if (l[i]) atomicAdd(&bucketCnt[i], l[i]);
}

// ---------------- bucket offsets scan ---------------------------------------
__global__ __launch_bounds__(512) void bucket_scan(const int* __restrict__ bucketCnt,
                                                   int* __restrict__ bucketOffs,
                                                   int* __restrict__ bucketCur) {
    __shared__ int s[512];
    int t = threadIdx.x;
    int v = bucketCnt[t];
    s[t] = v;
    __syncthreads();
    for (int off = 1; off < 512; off <<= 1) {
        int u = (t >= off) ? s[t - off] : 0;
        __syncthreads();
        s[t] += u;
        __syncthreads();
    }
    int excl = s[t] - v;
    bucketOffs[t] = excl;
    bucketCur[t] = excl;
    if (t == 511) bucketOffs[512] = s[511];
}

// ---------------- binned scatter: LDS counting-sort by bucket ----------------
__global__ __launch_bounds__(256) void binned_scatter(const int* __restrict__ src,
                                                      const int* __restrict__ dst,
                                                      int* __restrict__ bucketCur,
                                                      uint2* __restrict__ pairs) {
    __shared__ uint2 sorted[CHUNK];          // 64 KB
    __shared__ int lcnt[NB], loffs[NB], lcur[NB], gbase[NB];
    __shared__ int ps[256];
    int t = threadIdx.x;
    long e0 = (long)blockIdx.x * CHUNK;
    int nvalid = (int)min((long)CHUNK, (long)N_EDGES - e0);
    for (int i = t; i < NB; i += 256) lcnt[i] = 0;
    __syncthreads();
    for (int i = t; i < nvalid; i += 256)
        atomicAdd(&lcnt[(unsigned)dst[e0 + i] / NPB], 1);
    __syncthreads();
    int a0 = lcnt[2 * t], a1 = lcnt[2 * t + 1];
    ps[t] = a0 + a1;
    __syncthreads();
    for (int off = 1; off < 256; off <<= 1) {
        int u = (t >= off) ? ps[t - off] : 0;
        __syncthreads();
        ps[t] += u;
        __syncthreads();
    }
    int ex = ps[t] - (a0 + a1);
    loffs[2 * t] = ex; loffs[2 * t + 1] = ex + a0;
    lcur[2 * t] = ex;  lcur[2 * t + 1] = ex + a0;
    __syncthreads();
    for (int i = t; i < NB; i += 256) {
        int c = lcnt[i];
        gbase[i] = c ? atomicAdd(&bucketCur[i], c) : 0;
    }
    for (int i = t; i < nvalid; i += 256) {
        int d = dst[e0 + i];
        int b = (unsigned)d / NPB;
        int pos = atomicAdd(&lcur[b], 1);
        sorted[pos] = make_uint2((unsigned)src[e0 + i], (unsigned)d);
    }
    __syncthreads();
    for (int i = t; i < nvalid; i += 256) {
        uint2 pr = sorted[i];
        int b = pr.y / NPB;
        long gpos = (long)gbase[b] + (i - loffs[b]);
        pairs[gpos] = pr;
    }
}

// ---------------- per-bucket CSR finalize -----------------------------------
__global__ __launch_bounds__(256) void csr_finalize(const uint2* __restrict__ pairs,
                                                    const int* __restrict__ bucketOffs,
                                                    int* __restrict__ offs,
                                                    int* __restrict__ csr) {
    __shared__ uint2 lp[MAXE];     // 32 KB
    __shared__ int lsrc[MAXE];     // 16 KB
    __shared__ int lcnt[NPB], lofs[NPB + 1], lcur[NPB];
    __shared__ int ls[256];
    int b = blockIdx.x, t = threadIdx.x;
    int e0 = bucketOffs[b], e1 = bucketOffs[b + 1];
    int ne = e1 - e0;
    int n0 = b * NPB;
    int nn = min(NPB, N_NODES - n0);
    for (int i = t; i < ne; i += 256) lp[i] = pairs[e0 + i];
    for (int i = t; i < nn; i += 256) lcnt[i] = 0;
    __syncthreads();
    for (int i = t; i < ne; i += 256) atomicAdd(&lcnt[lp[i].y - n0], 1);
    __syncthreads();
    int v = (t < nn) ? lcnt[t] : 0;
    ls[t] = v;
    __syncthreads();
    for (int off = 1; off < 256; off <<= 1) {
        int u = (t >= off) ? ls[t - off] : 0;
        __syncthreads();
        ls[t] += u;
        __syncthreads();
    }
    if (t < nn) { lofs[t] = ls[t] - v; lcur[t] = ls[t] - v; offs[n0 + t] = e0 + ls[t] - v; }
    if (t == 0 && b == NBUSED - 1) offs[N_NODES] = e1;
    __syncthreads();
    for (int i = t; i < ne; i += 256) {
        int pos = atomicAdd(&lcur[lp[i].y - n0], 1);
        lsrc[pos] = (int)lp[i].x;
    }
    __syncthreads();
    for (int i = t; i < ne; i += 256) csr[e0 + i] = lsrc[i];
}

// --------- MFMA GEMM layer0: Yq[4][N][16] = bf16(h f32 [N][128]) @ bf16(w) --
#define SLABS 4
#define GEMM_BLOCKS 391
__global__ __launch_bounds__(256) void gemm0(const float* __restrict__ in,
                                             const float* __restrict__ w,
                                             ushort_t* __restrict__ y16) {
    __shared__ uint4 Bl[4][4][64];   // 16 KB: [kk][nt][lane] -> 8 bf16
    int t = threadIdx.x;
    for (int idx = t; idx < 4 * 4 * 64; idx += 256) {
        int l = idx & 63, nt = (idx >> 6) & 3, kk = idx >> 8;
        int k0 = kk * 32 + ((l >> 4) << 3), c = nt * 16 + (l & 15);
        uint4 o;
        o.x = (uint_t)f2b(w[(k0 + 0) * 64 + c]) | ((uint_t)f2b(w[(k0 + 1) * 64 + c]) << 16);
        o.y = (uint_t)f2b(w[(k0 + 2) * 64 + c]) | ((uint_t)f2b(w[(k0 + 3) * 64 + c]) << 16);
        o.z = (uint_t)f2b(w[(k0 + 4) * 64 + c]) | ((uint_t)f2b(w[(k0 + 5) * 64 + c]) << 16);
        o.w = (uint_t)f2b(w[(k0 + 6) * 64 + c]) | ((uint_t)f2b(w[(k0 + 7) * 64 + c]) << 16);
        Bl[kk][nt][l] = o;
    }
    __syncthreads();
    int wv = t >> 6, lane = t & 63, lq = lane >> 4, lr = lane & 15;
    bf16x8 B[4][4];
#pragma unroll
    for (int kk = 0; kk < 4; kk++)
#pragma unroll
        for (int nt = 0; nt < 4; nt++) { U4B8 cv; cv.u = Bl[kk][nt][lane]; B[kk][nt] = cv.v; }
    for (int s = 0; s < SLABS; s++) {
        long rb = ((long)blockIdx.x * SLABS + s) * 64 + wv * 16;
        long n = rb + lr;
        const float* rp = in + (n < N_NODES ? n : 0) * 128;
        f32x4 zero = {0.f, 0.f, 0.f, 0.f};
        f32x4 acc[4] = {zero, zero, zero, zero};
#pragma unroll
        for (int kk = 0; kk < 4; kk++) {
            float4 u = *(const float4*)(rp + kk * 32 + lq * 8);
            float4 v = *(const float4*)(rp + kk * 32 + lq * 8 + 4);
            bf16x8 a;
            a[0] = (short)f2b(u.x); a[1] = (short)f2b(u.y);
            a[2] = (short)f2b(u.z); a[3] = (short)f2b(u.w);
            a[4] = (short)f2b(v.x); a[5] = (short)f2b(v.y);
            a[6] = (short)f2b(v.z); a[7] = (short)f2b(v.w);
#pragma unroll
            for (int nt = 0; nt < 4; nt++)
                acc[nt] = __builtin_amdgcn_mfma_f32_16x16x32_bf16(a, B[kk][nt], acc[nt], 0, 0, 0);
        }
#pragma unroll
        for (int nt = 0; nt < 4; nt++)
#pragma unroll
            for (int j = 0; j < 4; j++) {
                long rr = rb + lq * 4 + j;
                if (rr < N_NODES)
                    y16[((long)nt * N_NODES + rr) * 16 + lr] = f2b(acc[nt][j]);
            }
    }
}

// --- MFMA GEMM + fused input BN/relu: out = relu(BN(in_bf16)) @ w ----------
// OSTAT=true: standard [N][64] output + column stats (fc2 path)
// OSTAT=false: quarter-split [4][N][16] output (fc1 path, feeds aggregate)
template <bool OSTAT>
__global__ __launch_bounds__(256) void gemm_bn(const uint4* __restrict__ in,
                                               const float* __restrict__ w,
                                               const float* __restrict__ bnip,
                                               const float* __restrict__ gi,
                                               const float* __restrict__ bi,
                                               ushort_t* __restrict__ outY,
                                               float* __restrict__ ostat) {
    __shared__ uint4 Bl[2][4][64];   // 8 KB
    __shared__ float sc[64], sh[64];
    __shared__ float red1[4][64], red2[4][64];
    int t = threadIdx.x;
    if (t < 64) {
        float S = 0.f, S2 = 0.f;
        for (int s = 0; s < NSLOT; s++) { S += bnip[s * 128 + t]; S2 += bnip[s * 128 + 64 + t]; }
        float mean = S * (1.f / N_NODES);
        float var = S2 * (1.f / N_NODES) - mean * mean;
        float r = rsqrtf(var + BN_EPS);
        float scv = gi[t] * r;
        sc[t] = scv; sh[t] = bi[t] - mean * scv;
    }
    for (int idx = t; idx < 2 * 4 * 64; idx += 256) {
        int l = idx & 63, nt = (idx >> 6) & 3, kk = idx >> 8;
        int k0 = kk * 32 + ((l >> 4) << 3), c = nt * 16 + (l & 15);
        uint4 o;
        o.x = (uint_t)f2b(w[(k0 + 0) * 64 + c]) | ((uint_t)f2b(w[(k0 + 1) * 64 + c]) << 16);
        o.y = (uint_t)f2b(w[(k0 + 2) * 64 + c]) | ((uint_t)f2b(w[(k0 + 3) * 64 + c]) << 16);
        o.z = (uint_t)f2b(w[(k0 + 4) * 64 + c]) | ((uint_t)f2b(w[(k0 + 5) * 64 + c]) << 16);
        o.w = (uint_t)f2b(w[(k0 + 6) * 64 + c]) | ((uint_t)f2b(w[(k0 + 7) * 64 + c]) << 16);
        Bl[kk][nt][l] = o;
    }
    __syncthreads();
    int wv = t >> 6, lane = t & 63, lq = lane >> 4, lr = lane & 15;
    bf16x8 B[2][4];
#pragma unroll
    for (int kk = 0; kk < 2; kk++)
#pragma unroll
        for (int nt = 0; nt < 4; nt++) { U4B8 cv; cv.u = Bl[kk][nt][lane]; B[kk][nt] = cv.v; }
    float s1[4] = {0.f, 0.f, 0.f, 0.f}, s2[4] = {0.f, 0.f, 0.f, 0.f};
    for (int s = 0; s < SLABS; s++) {
        long rb = ((long)blockIdx.x * SLABS + s) * 64 + wv * 16;
        long n = rb + lr;
        bool ok = n < N_NODES;
        const uint4* rp = in + (ok ? n : 0) * 8;
        f32x4 zero = {0.f, 0.f, 0.f, 0.f};
        f32x4 acc[4] = {zero, zero, zero, zero};
#pragma unroll
        for (int kk = 0; kk < 2; kk++) {
            bf16x8 a;
            if (ok) {
                uint4 v = rp[kk * 4 + lq];
                int k0 = kk * 32 + lq * 8;
                float x0 = fmaxf(blo(v.x) * sc[k0 + 0] + sh[k0 + 0], 0.f);
                float x1 = fmaxf(bhi(v.x) * sc[k0 + 1] + sh[k0 + 1], 0.f);
                float x2 = fmaxf(blo(v.y) * sc[k0 + 2] + sh[k0 + 2], 0.f);
                float x3 = fmaxf(bhi(v.y) * sc[k0 + 3] + sh[k0 + 3], 0.f);
                float x4 = fmaxf(blo(v.z) * sc[k0 + 4] + sh[k0 + 4], 0.f);
                float x5 = fmaxf(bhi(v.z) * sc[k0 + 5] + sh[k0 + 5], 0.f);
                float x6 = fmaxf(blo(v.w) * sc[k0 + 6] + sh[k0 + 6], 0.f);
                float x7 = fmaxf(bhi(v.w) * sc[k0 + 7] + sh[k0 + 7], 0.f);
                a[0] = (short)f2b(x0); a[1] = (short)f2b(x1);
                a[2] = (short)f2b(x2); a[3] = (short)f2b(x3);
                a[4] = (short)f2b(x4); a[5] = (short)f2b(x5);
                a[6] = (short)f2b(x6); a[7] = (short)f2b(x7);
            } else {
#pragma unroll
                for (int j = 0; j < 8; j++) a[j] = 0;
            }
#pragma unroll
            for (int nt = 0; nt < 4; nt++)
                acc[nt] = __builtin_amdgcn_mfma_f32_16x16x32_bf16(a, B[kk][nt], acc[nt], 0, 0, 0);
        }
#pragma unroll
        for (int nt = 0; nt < 4; nt++)
#pragma unroll
            for (int j = 0; j < 4; j++) {
                long rr = rb + lq * 4 + j;
                float val = acc[nt][j];
                if (rr < N_NODES) {
                    if (OSTAT) outY[rr * 64 + nt * 16 + lr] = f2b(val);
                    else       outY[((long)nt * N_NODES + rr) * 16 + lr] = f2b(val);
                }
                if (OSTAT) { s1[nt] += val; s2[nt] += val * val; }
            }
    }
    if (OSTAT) {
#pragma unroll
        for (int nt = 0; nt < 4; nt++) {
            s1[nt] += __shfl_xor(s1[nt], 16); s1[nt] += __shfl_xor(s1[nt], 32);
            s2[nt] += __shfl_xor(s2[nt], 16); s2[nt] += __shfl_xor(s2[nt], 32);
        }
        if (lq == 0) {
#pragma unroll
            for (int nt = 0; nt < 4; nt++) {
                red1[wv][nt * 16 + lr] = s1[nt];
                red2[wv][nt * 16 + lr] = s2[nt];
            }
        }
        __syncthreads();
        if (t < 64) {
            float S = red1[0][t] + red1[1][t] + red1[2][t] + red1[3][t];
            float S2 = red2[0][t] + red2[1][t] + red2[2][t] + red2[3][t];
            int slot = blockIdx.x & (NSLOT - 1);
            atomicAdd(&ostat[slot * 128 + t], S);
            atomicAdd(&ostat[slot * 128 + 64 + t], S2);
        }
    }
}

// ------- aggregation (quarter-partitioned, L2-resident): ---------------------
// grid = 3125 chunks x 4 quarters; q = blockIdx%4 aligns with XCD round-robin
// lane = (edge-slot = lane>>1, half = lane&1); 16B loads; 32 edges/instr
__global__ __launch_bounds__(256) void aggregate(const uint_t* __restrict__ yq_all,
                                                 const int* __restrict__ offs,
                                                 const int* __restrict__ csr,
                                                 uint_t* __restrict__ aggOut,
                                                 float* __restrict__ bn1p) {
    int t = threadIdx.x;
    int wv = t >> 6, lane = t & 63;
    int slot = lane >> 1, h = lane & 1;
    int b = blockIdx.x;
    int q = b & 3, chunk = b >> 2;
    const uint_t* yq = yq_all + (long)q * N_NODES * 8;
    __shared__ float l1[4][16], l2[4][16];
    float st1[8], st2[8];
#pragma unroll
    for (int m = 0; m < 8; m++) { st1[m] = 0.f; st2[m] = 0.f; }
    int nb_base = chunk * 32 + wv * 8;      // 3125*32 == N_NODES exactly
    for (int j = 0; j < 8; j++) {
        int n = nb_base + j;
        int p0 = offs[n], p1 = offs[n + 1];
        int cnt = 1 + (p1 - p0);            // self + neighbors
        int rounds = (cnt + 31) >> 5;
        float accA[4] = {0.f, 0.f, 0.f, 0.f}, accB[4] = {0.f, 0.f, 0.f, 0.f};
        int e = slot;
        int idx = (slot == 0) ? n : ((slot < cnt) ? csr[p0 + slot - 1] : -1);
        for (int r = 0; r < rounds; r++) {
            int ne = e + 32;
            int nidx = (ne < cnt) ? csr[p0 + ne - 1] : -1;
            if (idx >= 0) {
                uint4 v = *(const uint4*)(yq + (long)idx * 8 + h * 4);
                accA[0] += __uint_as_float(v.x << 16);
                accB[0] += __uint_as_float(v.x & 0xffff0000u);
                accA[1] += __uint_as_float(v.y << 16);
                accB[1] += __uint_as_float(v.y & 0xffff0000u);
                accA[2] += __uint_as_float(v.z << 16);
                accB[2] += __uint_as_float(v.z & 0xffff0000u);
                accA[3] += __uint_as_float(v.w << 16);
                accB[3] += __uint_as_float(v.w & 0xffff0000u);
            }
            e = ne; idx = nidx;
        }
#pragma unroll
        for (int m = 0; m < 4; m++) {
            accA[m] += __shfl_xor(accA[m], 2);
            accB[m] += __shfl_xor(accB[m], 2);
            accA[m] += __shfl_xor(accA[m], 4);
            accB[m] += __shfl_xor(accB[m], 4);
            accA[m] += __shfl_xor(accA[m], 8);
            accB[m] += __shfl_xor(accB[m], 8);
            accA[m] += __shfl_xor(accA[m], 16);
            accB[m] += __shfl_xor(accB[m], 16);
            accA[m] += __shfl_xor(accA[m], 32);
            accB[m] += __shfl_xor(accB[m], 32);
        }
        if (slot == 0) {
            uint4 o;
            o.x = (uint_t)f2b(accA[0]) | ((uint_t)f2b(accB[0]) << 16);
            o.y = (uint_t)f2b(accA[1]) | ((uint_t)f2b(accB[1]) << 16);
            o.z = (uint_t)f2b(accA[2]) | ((uint_t)f2b(accB[2]) << 16);
            o.w = (uint_t)f2b(accA[3]) | ((uint_t)f2b(accB[3]) << 16);
            *(uint4*)&aggOut[(long)n * 32 + q * 8 + h * 4] = o;
            st1[0] += accA[0]; st2[0] += accA[0] * accA[0];
            st1[1] += accB[0]; st2[1] += accB[0] * accB[0];
            st1[2] += accA[1]; st2[2] += accA[1] * accA[1];
            st1[3] += accB[1]; st2[3] += accB[1] * accB[1];
            st1[4] += accA[2]; st2[4] += accA[2] * accA[2];
            st1[5] += accB[2]; st2[5] += accB[2] * accB[2];
            st1[6] += accA[3]; st2[6] += accA[3] * accA[3];
            st1[7] += accB[3]; st2[7] += accB[3] * accB[3];
        }
    }
    if (slot == 0) {
#pragma unroll
        for (int m = 0; m < 8; m++) {
            l1[wv][h * 8 + m] = st1[m];
            l2[wv][h * 8 + m] = st2[m];
        }
    }
    __syncthreads();
    if (t < 16) {
        float S = l1[0][t] + l1[1][t] + l1[2][t] + l1[3][t];
        float S2 = l2[0][t] + l2[1][t] + l2[2][t] + l2[3][t];
        int slotc = blockIdx.x & (NSLOT - 1);
        atomicAdd(&bn1p[slotc * 128 + q * 16 + t], S);
        atomicAdd(&bn1p[slotc * 128 + 64 + q * 16 + t], S2);
    }
}

// --- pooled[g] += relu(BN2(h2)) (sorted graph_ids) --------------------------
__global__ __launch_bounds__(256) void bn_pool(const uint_t* __restrict__ h2,
                                               const float* __restrict__ bn2p,
                                               const float* __restrict__ g2,
                                               const float* __restrict__ b2,
                                               const int* __restrict__ gid,
                                               float* __restrict__ pooled) {
    __shared__ float sc[64], sh[64];
    int t = threadIdx.x;
    if (t < 64) {
        float S = 0.f, S2 = 0.f;
        for (int s = 0; s < NSLOT; s++) { S += bn2p[s * 128 + t]; S2 += bn2p[s * 128 + 64 + t]; }
        float mean = S * (1.f / N_NODES);
        float var = S2 * (1.f / N_NODES) - mean * mean;
        float r = rsqrtf(var + BN_EPS);
        float scv = g2[t] * r;
        sc[t] = scv; sh[t] = b2[t] - mean * scv;
    }
    __syncthreads();
    int c = t & 31, rs = t >> 5;
    float sA = sc[2 * c], hA = sh[2 * c], sB = sc[2 * c + 1], hB = sh[2 * c + 1];
    long base = (long)blockIdx.x * 256;
    float pa = 0.f, pb2 = 0.f; int gc = -1;
    for (int i = 0; i < 32; i++) {
        long n = base + rs + 8 * i;
        if (n >= N_NODES) break;
        int g = gid[n];
        uint_t v = h2[n * 32 + c];
        float x0 = fmaxf(blo(v) * sA + hA, 0.f);
        float x1 = fmaxf(bhi(v) * sB + hB, 0.f);
        if (g != gc) {
            if (gc >= 0) {
                atomicAdd(&pooled[(long)gc * 64 + 2 * c], pa);
                atomicAdd(&pooled[(long)gc * 64 + 2 * c + 1], pb2);
            }
            gc = g; pa = 0.f; pb2 = 0.f;
        }
        pa += x0; pb2 += x1;
    }
    if (gc >= 0) {
        atomicAdd(&pooled[(long)gc * 64 + 2 * c], pa);
        atomicAdd(&pooled[(long)gc * 64 + 2 * c + 1], pb2);
    }
}

// --------- score = sum_l pooled_l @ pred_w_l + pred_b_l --------------------
__global__ __launch_bounds__(256) void score_kernel(const float* __restrict__ pooled,
                                                    const float* __restrict__ pw,
                                                    const float* __restrict__ pb,
                                                    float* __restrict__ out) {
    int idx = blockIdx.x * 256 + threadIdx.x;  // 16384 = 512*32
    int g = idx >> 5, o = idx & 31;
    float acc = 0.f;
    for (int l = 0; l < N_CONV; l++) {
        acc += pb[l * 32 + o];
        const float* pr = pooled + (long)l * N_GRAPHS * 64 + (long)g * 64;
        const float* wr = pw + l * 64 * 32;
        for (int k = 0; k < 64; k++) acc += pr[k] * wr[k * 32 + o];
    }
    out[idx] = acc;
}

extern "C" void kernel_launch(void* const* d_in, const int* in_sizes, int n_in,
                              void* d_out, int out_size, void* d_ws, size_t ws_size,
                              hipStream_t stream) {
    const float* h     = (const float*)d_in[0];
    const int*   src   = (const int*)d_in[1];
    const int*   dst   = (const int*)d_in[2];
    const int*   gid   = (const int*)d_in[3];
    const float* fc1w0 = (const float*)d_in[4];
    const float* fc1w  = (const float*)d_in[5];
    const float* fc2w  = (const float*)d_in[6];
    const float* bn1g  = (const float*)d_in[7];
    const float* bn1b  = (const float*)d_in[8];
    const float* bn2g  = (const float*)d_in[9];
    const float* bn2b  = (const float*)d_in[10];
    const float* pw    = (const float*)d_in[11];
    const float* pb    = (const float*)d_in[12];
    float* out = (float*)d_out;

    char* ws = (char*)d_ws;
    uint_t*   AGG16   = (uint_t*)  (ws);              // agg bf16 [N][64]: 12,800,000
    uint2*    pairs   = (uint2*)   (ws);              // alias; dead before layer-0 aggregate
    ushort_t* X16     = (ushort_t*)(ws + 25600000);   // h2 bf16 [N][64]: 12,800,000
    ushort_t* Y16     = (ushort_t*)(ws + 38400000);   // y bf16 quarter-split [4][N][16]: 12,800,000
    float*    bnst    = (float*)   (ws + 51200000);   // 131,072
    float*    pooled  = (float*)   (ws + 51331072);   // 524,288
    int*   bucketCnt  = (int*)     (ws + 51855360);   // 2,048
    int*   bucketOffs = (int*)     (ws + 51857408);   // 2,052
    int*   bucketCur  = (int*)     (ws + 51859460);   // 2,048
    int*   offs       = (int*)     (ws + 51861508);   // 400,004
    int*   csr        = (int*)     (ws + 52261512);   // 6,400,000 (end 58,661,512)

    // zero: bnst + pooled + bucketCnt (contiguous: 51,200,000 .. 51,857,408)
    const int zwords = (51857408 - 51200000) / 4;     // 164,352
    zero_kernel<<<(zwords + 255) / 256, 256, 0, stream>>>((int*)bnst, zwords);

    bucket_count<<<(N_EDGES + 4095) / 4096, 256, 0, stream>>>(dst, bucketCnt);
    bucket_scan<<<1, 512, 0, stream>>>(bucketCnt, bucketOffs, bucketCur);
    binned_scatter<<<(N_EDGES + CHUNK - 1) / CHUNK, 256, 0, stream>>>(src, dst, bucketCur, pairs);
    csr_finalize<<<NBUSED, 256, 0, stream>>>(pairs, bucketOffs, offs, csr);

    for (int l = 0; l < N_CONV; l++) {
        float* bn1p = bnst + (long)l * 8192;
        float* bn2p = bn1p + 4096;
        float* pl = pooled + (long)l * N_GRAPHS * 64;
        if (l == 0) {
            gemm0<<<GEMM_BLOCKS, 256, 0, stream>>>(h, fc1w0, Y16);
        } else {
            float* bn2p_prev = bnst + (long)(l - 1) * 8192 + 4096;
            gemm_bn<false><<<GEMM_BLOCKS, 256, 0, stream>>>((const uint4*)X16,
                fc1w + (long)(l - 1) * 4096, bn2p_prev,
                bn2g + (l - 1) * 64, bn2b + (l - 1) * 64, Y16, (float*)nullptr);
        }
        aggregate<<<3125 * 4, 256, 0, stream>>>((const uint_t*)Y16, offs, csr, AGG16, bn1p);
        gemm_bn<true><<<GEMM_BLOCKS, 256, 0, stream>>>((const uint4*)AGG16,
            fc2w + (long)l * 4096, bn1p, bn1g + l * 64, bn1b + l * 64, X16, bn2p);
        bn_pool<<<391, 256, 0, stream>>>((const uint_t*)X16, bn2p, bn2g + l * 64,
                                         bn2b + l * 64, gid, pl);
    }
    score_kernel<<<64, 256, 0, stream>>>(pooled, pw, pb, out);
}

// Round 10
// 509.153 us; speedup vs baseline: 1.7785x; 1.7785x over previous
//
#include <hip/hip_runtime.h>

#define N_NODES 100000
#define N_EDGES 1600000
#define N_GRAPHS 512
#define D_IN 128
#define D_H 64
#define D_OUT 32
#define N_CONV 4
#define BN_EPS 1e-5f
#define NSLOT 32

#define NB 512        // buckets
#define NPB 196       // nodes per bucket
#define NBUSED 511
#define CHUNK 8192    // edges per binned_scatter block
#define MAXE 4096     // max edges per bucket (mean 3136)
#define AGG_BLOCKS 2048
#define AGG_CHUNKS 3125

typedef unsigned short ushort_t;
typedef unsigned int uint_t;
typedef __attribute__((ext_vector_type(8))) short bf16x8;
typedef __attribute__((ext_vector_type(4))) float f32x4;
union U4B8 { uint4 u; bf16x8 v; };

__device__ inline float b2f(ushort_t u) {
    union { uint_t i; float f; } c; c.i = ((uint_t)u) << 16; return c.f;
}
__device__ inline ushort_t f2b(float f) {
    union { uint_t i; float f; } c; c.f = f;
    uint_t r = (c.i + 0x7fffu + ((c.i >> 16) & 1u)) >> 16;
    return (ushort_t)r;
}
__device__ inline float blo(uint_t v) { return b2f((ushort_t)(v & 0xffffu)); }
__device__ inline float bhi(uint_t v) { return b2f((ushort_t)(v >> 16)); }

// ---------------- utility: zero a region ------------------------------------
__global__ __launch_bounds__(256) void zero_kernel(int* __restrict__ p, int nwords) {
    int i = blockIdx.x * 256 + threadIdx.x;
    if (i < nwords) p[i] = 0;
}

// ---------------- CSR build: bucket histogram -------------------------------
__global__ __launch_bounds__(256) void bucket_count(const int* __restrict__ dst,
                                                    int* __restrict__ bucketCnt) {
    __shared__ int l[NB];
    int t = threadIdx.x;
    for (int i = t; i < NB; i += 256) l[i] = 0;
    __syncthreads();
    long base = (long)blockIdx.x * 4096;
    for (int i = t; i < 4096; i += 256) {
        long e = base + i;
        if (e < N_EDGES) atomicAdd(&l[(unsigned)dst[e] / NPB], 1);
    }
    __syncthreads();
    for (int i = t; i < NB; i += 256) if (l[i]) atomicAdd(&bucketCnt[i], l[i]);
}

// ---------------- bucket offsets scan ---------------------------------------
__global__ __launch_bounds__(512) void bucket_scan(const int* __restrict__ bucketCnt,
                                                   int* __restrict__ bucketOffs,
                                                   int* __restrict__ bucketCur) {
    __shared__ int s[512];
    int t = threadIdx.x;
    int v = bucketCnt[t];
    s[t] = v;
    __syncthreads();
    for (int off = 1; off < 512; off <<= 1) {
        int u = (t >= off) ? s[t - off] : 0;
        __syncthreads();
        s[t] += u;
        __syncthreads();
    }
    int excl = s[t] - v;
    bucketOffs[t] = excl;
    bucketCur[t] = excl;
    if (t == 511) bucketOffs[512] = s[511];
}

// ------- binned scatter: LDS counting-sort by bucket; packed 26-bit pairs ----
__global__ __launch_bounds__(256) void binned_scatter(const int* __restrict__ src,
                                                      const int* __restrict__ dst,
                                                      int* __restrict__ bucketCur,
                                                      uint_t* __restrict__ pairs) {
    __shared__ uint_t sortedp[CHUNK];        // 32 KB
    __shared__ ushort_t sbkt[CHUNK];         // 16 KB
    __shared__ int lcnt[NB], loffs[NB], lcur[NB], gbase[NB];
    __shared__ int ps[256];
    int t = threadIdx.x;
    long e0 = (long)blockIdx.x * CHUNK;
    int nvalid = (int)min((long)CHUNK, (long)N_EDGES - e0);
    for (int i = t; i < NB; i += 256) lcnt[i] = 0;
    __syncthreads();
    for (int i = t; i < nvalid; i += 256)
        atomicAdd(&lcnt[(unsigned)dst[e0 + i] / NPB], 1);
    __syncthreads();
    int a0 = lcnt[2 * t], a1 = lcnt[2 * t + 1];
    ps[t] = a0 + a1;
    __syncthreads();
    for (int off = 1; off < 256; off <<= 1) {
        int u = (t >= off) ? ps[t - off] : 0;
        __syncthreads();
        ps[t] += u;
        __syncthreads();
    }
    int ex = ps[t] - (a0 + a1);
    loffs[2 * t] = ex; loffs[2 * t + 1] = ex + a0;
    lcur[2 * t] = ex;  lcur[2 * t + 1] = ex + a0;
    __syncthreads();
    for (int i = t; i < NB; i += 256) {
        int c = lcnt[i];
        gbase[i] = c ? atomicAdd(&bucketCur[i], c) : 0;
    }
    for (int i = t; i < nvalid; i += 256) {
        int d = dst[e0 + i];
        int b = (unsigned)d / NPB;
        int pos = atomicAdd(&lcur[b], 1);
        sortedp[pos] = ((uint_t)src[e0 + i] << 9) | (uint_t)(d - b * NPB);
        sbkt[pos] = (ushort_t)b;
    }
    __syncthreads();
    for (int i = t; i < nvalid; i += 256) {
        int b = sbkt[i];
        long gpos = (long)gbase[b] + (i - loffs[b]);
        pairs[gpos] = sortedp[i];
    }
}

// ---------------- per-bucket CSR finalize (packed pairs) --------------------
__global__ __launch_bounds__(256) void csr_finalize(const uint_t* __restrict__ pairs,
                                                    const int* __restrict__ bucketOffs,
                                                    int* __restrict__ offs,
                                                    int* __restrict__ csr) {
    __shared__ uint_t lp[MAXE];    // 16 KB
    __shared__ int lsrc[MAXE];     // 16 KB
    __shared__ int lcnt[NPB], lcur[NPB];
    __shared__ int ls[256];
    int b = blockIdx.x, t = threadIdx.x;
    int e0 = bucketOffs[b], e1 = bucketOffs[b + 1];
    int ne = e1 - e0;
    int n0 = b * NPB;
    int nn = min(NPB, N_NODES - n0);
    for (int i = t; i < ne; i += 256) lp[i] = pairs[e0 + i];
    for (int i = t; i < nn; i += 256) lcnt[i] = 0;
    __syncthreads();
    for (int i = t; i < ne; i += 256) atomicAdd(&lcnt[lp[i] & 511u], 1);
    __syncthreads();
    int v = (t < nn) ? lcnt[t] : 0;
    ls[t] = v;
    __syncthreads();
    for (int off = 1; off < 256; off <<= 1) {
        int u = (t >= off) ? ls[t - off] : 0;
        __syncthreads();
        ls[t] += u;
        __syncthreads();
    }
    if (t < nn) { lcur[t] = ls[t] - v; offs[n0 + t] = e0 + ls[t] - v; }
    if (t == 0 && b == NBUSED - 1) offs[N_NODES] = e1;
    __syncthreads();
    for (int i = t; i < ne; i += 256) {
        uint_t p = lp[i];
        int pos = atomicAdd(&lcur[p & 511u], 1);
        lsrc[pos] = (int)(p >> 9);
    }
    __syncthreads();
    for (int i = t; i < ne; i += 256) csr[e0 + i] = lsrc[i];
}

// --------- MFMA GEMM layer0: y16[N][64] = bf16(h f32 [N][128]) @ bf16(w) ----
#define SLABS 4
#define GEMM_BLOCKS 391
__global__ __launch_bounds__(256) void gemm0(const float* __restrict__ in,
                                             const float* __restrict__ w,
                                             ushort_t* __restrict__ y16) {
    __shared__ uint4 Bl[4][4][64];   // 16 KB
    int t = threadIdx.x;
    for (int idx = t; idx < 4 * 4 * 64; idx += 256) {
        int l = idx & 63, nt = (idx >> 6) & 3, kk = idx >> 8;
        int k0 = kk * 32 + ((l >> 4) << 3), c = nt * 16 + (l & 15);
        uint4 o;
        o.x = (uint_t)f2b(w[(k0 + 0) * 64 + c]) | ((uint_t)f2b(w[(k0 + 1) * 64 + c]) << 16);
        o.y = (uint_t)f2b(w[(k0 + 2) * 64 + c]) | ((uint_t)f2b(w[(k0 + 3) * 64 + c]) << 16);
        o.z = (uint_t)f2b(w[(k0 + 4) * 64 + c]) | ((uint_t)f2b(w[(k0 + 5) * 64 + c]) << 16);
        o.w = (uint_t)f2b(w[(k0 + 6) * 64 + c]) | ((uint_t)f2b(w[(k0 + 7) * 64 + c]) << 16);
        Bl[kk][nt][l] = o;
    }
    __syncthreads();
    int wv = t >> 6, lane = t & 63, lq = lane >> 4, lr = lane & 15;
    bf16x8 B[4][4];
#pragma unroll
    for (int kk = 0; kk < 4; kk++)
#pragma unroll
        for (int nt = 0; nt < 4; nt++) { U4B8 cv; cv.u = Bl[kk][nt][lane]; B[kk][nt] = cv.v; }
    for (int s = 0; s < SLABS; s++) {
        long rb = ((long)blockIdx.x * SLABS + s) * 64 + wv * 16;
        long n = rb + lr;
        const float* rp = in + (n < N_NODES ? n : 0) * 128;
        f32x4 zero = {0.f, 0.f, 0.f, 0.f};
        f32x4 acc[4] = {zero, zero, zero, zero};
#pragma unroll
        for (int kk = 0; kk < 4; kk++) {
            float4 u = *(const float4*)(rp + kk * 32 + lq * 8);
            float4 v = *(const float4*)(rp + kk * 32 + lq * 8 + 4);
            bf16x8 a;
            a[0] = (short)f2b(u.x); a[1] = (short)f2b(u.y);
            a[2] = (short)f2b(u.z); a[3] = (short)f2b(u.w);
            a[4] = (short)f2b(v.x); a[5] = (short)f2b(v.y);
            a[6] = (short)f2b(v.z); a[7] = (short)f2b(v.w);
#pragma unroll
            for (int nt = 0; nt < 4; nt++)
                acc[nt] = __builtin_amdgcn_mfma_f32_16x16x32_bf16(a, B[kk][nt], acc[nt], 0, 0, 0);
        }
#pragma unroll
        for (int nt = 0; nt < 4; nt++)
#pragma unroll
            for (int j = 0; j < 4; j++) {
                long rr = rb + lq * 4 + j;
                if (rr < N_NODES) y16[rr * 64 + nt * 16 + lr] = f2b(acc[nt][j]);
            }
    }
}

// --- MFMA GEMM + fused input BN/relu: out = relu(BN(in_bf16)) @ w -----------
// OSTAT: accumulate output column stats (fc2). POOL: accumulate per-graph
// pooled sums of the relu'd INPUT values (pool of the previous layer).
template <bool OSTAT, bool POOL>
__global__ __launch_bounds__(256) void gemm_bn(const uint4* __restrict__ in,
                                               const float* __restrict__ w,
                                               const float* __restrict__ bnip,
                                               const float* __restrict__ gi,
                                               const float* __restrict__ bi,
                                               ushort_t* __restrict__ outY,
                                               float* __restrict__ ostat,
                                               const int* __restrict__ gid,
                                               float* __restrict__ pooledPrev) {
    __shared__ uint4 Bl[2][4][64];   // 8 KB
    __shared__ float sc[64], sh[64];
    __shared__ float red1[4][64], red2[4][64];
    __shared__ float lds_pool[8][64];
    int t = threadIdx.x;
    if (t < 64) {
        float S = 0.f, S2 = 0.f;
        for (int s = 0; s < NSLOT; s++) { S += bnip[s * 128 + t]; S2 += bnip[s * 128 + 64 + t]; }
        float mean = S * (1.f / N_NODES);
        float var = S2 * (1.f / N_NODES) - mean * mean;
        float r = rsqrtf(var + BN_EPS);
        float scv = gi[t] * r;
        sc[t] = scv; sh[t] = bi[t] - mean * scv;
    }
    if (POOL) {
        for (int i = t; i < 8 * 64; i += 256) lds_pool[i >> 6][i & 63] = 0.f;
    }
    for (int idx = t; idx < 2 * 4 * 64; idx += 256) {
        int l = idx & 63, nt = (idx >> 6) & 3, kk = idx >> 8;
        int k0 = kk * 32 + ((l >> 4) << 3), c = nt * 16 + (l & 15);
        uint4 o;
        o.x = (uint_t)f2b(w[(k0 + 0) * 64 + c]) | ((uint_t)f2b(w[(k0 + 1) * 64 + c]) << 16);
        o.y = (uint_t)f2b(w[(k0 + 2) * 64 + c]) | ((uint_t)f2b(w[(k0 + 3) * 64 + c]) << 16);
        o.z = (uint_t)f2b(w[(k0 + 4) * 64 + c]) | ((uint_t)f2b(w[(k0 + 5) * 64 + c]) << 16);
        o.w = (uint_t)f2b(w[(k0 + 6) * 64 + c]) | ((uint_t)f2b(w[(k0 + 7) * 64 + c]) << 16);
        Bl[kk][nt][l] = o;
    }
    __syncthreads();
    int wv = t >> 6, lane = t & 63, lq = lane >> 4, lr = lane & 15;
    int g_base = POOL ? gid[blockIdx.x * 256] : 0;   // first row of block (<N_NODES)
    bf16x8 B[2][4];
#pragma unroll
    for (int kk = 0; kk < 2; kk++)
#pragma unroll
        for (int nt = 0; nt < 4; nt++) { U4B8 cv; cv.u = Bl[kk][nt][lane]; B[kk][nt] = cv.v; }
    float s1[4] = {0.f, 0.f, 0.f, 0.f}, s2[4] = {0.f, 0.f, 0.f, 0.f};
    for (int s = 0; s < SLABS; s++) {
        long rb = ((long)blockIdx.x * SLABS + s) * 64 + wv * 16;
        long n = rb + lr;
        bool ok = n < N_NODES;
        const uint4* rp = in + (ok ? n : 0) * 8;
        int gl = 0;
        if (POOL && ok) gl = gid[n] - g_base;
        f32x4 zero = {0.f, 0.f, 0.f, 0.f};
        f32x4 acc[4] = {zero, zero, zero, zero};
#pragma unroll
        for (int kk = 0; kk < 2; kk++) {
            bf16x8 a;
            if (ok) {
                uint4 v = rp[kk * 4 + lq];
                int k0 = kk * 32 + lq * 8;
                float x0 = fmaxf(blo(v.x) * sc[k0 + 0] + sh[k0 + 0], 0.f);
                float x1 = fmaxf(bhi(v.x) * sc[k0 + 1] + sh[k0 + 1], 0.f);
                float x2 = fmaxf(blo(v.y) * sc[k0 + 2] + sh[k0 + 2], 0.f);
                float x3 = fmaxf(bhi(v.y) * sc[k0 + 3] + sh[k0 + 3], 0.f);
                float x4 = fmaxf(blo(v.z) * sc[k0 + 4] + sh[k0 + 4], 0.f);
                float x5 = fmaxf(bhi(v.z) * sc[k0 + 5] + sh[k0 + 5], 0.f);
                float x6 = fmaxf(blo(v.w) * sc[k0 + 6] + sh[k0 + 6], 0.f);
                float x7 = fmaxf(bhi(v.w) * sc[k0 + 7] + sh[k0 + 7], 0.f);
                if (POOL) {
                    if (gl < 8) {
                        atomicAdd(&lds_pool[gl][k0 + 0], x0);
                        atomicAdd(&lds_pool[gl][k0 + 1], x1);
                        atomicAdd(&lds_pool[gl][k0 + 2], x2);
                        atomicAdd(&lds_pool[gl][k0 + 3], x3);
                        atomicAdd(&lds_pool[gl][k0 + 4], x4);
                        atomicAdd(&lds_pool[gl][k0 + 5], x5);
                        atomicAdd(&lds_pool[gl][k0 + 6], x6);
                        atomicAdd(&lds_pool[gl][k0 + 7], x7);
                    } else {
                        long pb = (long)(g_base + gl) * 64 + k0;
                        atomicAdd(&pooledPrev[pb + 0], x0);
                        atomicAdd(&pooledPrev[pb + 1], x1);
                        atomicAdd(&pooledPrev[pb + 2], x2);
                        atomicAdd(&pooledPrev[pb + 3], x3);
                        atomicAdd(&pooledPrev[pb + 4], x4);
                        atomicAdd(&pooledPrev[pb + 5], x5);
                        atomicAdd(&pooledPrev[pb + 6], x6);
                        atomicAdd(&pooledPrev[pb + 7], x7);
                    }
                }
                a[0] = (short)f2b(x0); a[1] = (short)f2b(x1);
                a[2] = (short)f2b(x2); a[3] = (short)f2b(x3);
                a[4] = (short)f2b(x4); a[5] = (short)f2b(x5);
                a[6] = (short)f2b(x6); a[7] = (short)f2b(x7);
            } else {
#pragma unroll
                for (int j = 0; j < 8; j++) a[j] = 0;
            }
#pragma unroll
            for (int nt = 0; nt < 4; nt++)
                acc[nt] = __builtin_amdgcn_mfma_f32_16x16x32_bf16(a, B[kk][nt], acc[nt], 0, 0, 0);
        }
#pragma unroll
        for (int nt = 0; nt < 4; nt++)
#pragma unroll
            for (int j = 0; j < 4; j++) {
                long rr = rb + lq * 4 + j;
                float val = acc[nt][j];
                if (rr < N_NODES) outY[rr * 64 + nt * 16 + lr] = f2b(val);
                if (OSTAT) { s1[nt] += val; s2[nt] += val * val; }
            }
    }
    if (OSTAT) {
#pragma unroll
        for (int nt = 0; nt < 4; nt++) {
            s1[nt] += __shfl_xor(s1[nt], 16); s1[nt] += __shfl_xor(s1[nt], 32);
            s2[nt] += __shfl_xor(s2[nt], 16); s2[nt] += __shfl_xor(s2[nt], 32);
        }
        if (lq == 0) {
#pragma unroll
            for (int nt = 0; nt < 4; nt++) {
                red1[wv][nt * 16 + lr] = s1[nt];
                red2[wv][nt * 16 + lr] = s2[nt];
            }
        }
        __syncthreads();
        if (t < 64) {
            float S = red1[0][t] + red1[1][t] + red1[2][t] + red1[3][t];
            float S2 = red2[0][t] + red2[1][t] + red2[2][t] + red2[3][t];
            int slot = blockIdx.x & (NSLOT - 1);
            atomicAdd(&ostat[slot * 128 + t], S);
            atomicAdd(&ostat[slot * 128 + 64 + t], S2);
        }
    }
    if (POOL) {
        __syncthreads();
        for (int i = t; i < 8 * 64; i += 256) {
            float v = lds_pool[i >> 6][i & 63];
            if (v != 0.f) {
                int gg = g_base + (i >> 6);
                if (gg < N_GRAPHS)
                    atomicAdd(&pooledPrev[(long)gg * 64 + (i & 63)], v);
            }
        }
    }
}

// ------- aggregation: agg16 = y16 + sum_nb y16[nb] + BN1 stats --------------
// persistent grid (2048 blocks); 8 edge-slots x 8 col-chunks; value prefetch
__global__ __launch_bounds__(256) void aggregate(const uint_t* __restrict__ y32,
                                                 const int* __restrict__ offs,
                                                 const int* __restrict__ csr,
                                                 uint_t* __restrict__ aggOut,
                                                 float* __restrict__ bn1p) {
    int t = threadIdx.x;
    int wv = t >> 6, lane = t & 63;
    int g = lane >> 3, l = lane & 7;
    __shared__ float l1[4][64], l2[4][64];
    float st1[8], st2[8];
#pragma unroll
    for (int m = 0; m < 8; m++) { st1[m] = 0.f; st2[m] = 0.f; }
    for (int chunk = blockIdx.x; chunk < AGG_CHUNKS; chunk += AGG_BLOCKS) {
        int nb_base = chunk * 32 + wv * 8;
        for (int j = 0; j < 8; j++) {
            int n = nb_base + j;
            int p0 = offs[n], p1 = offs[n + 1];
            int cnt = 1 + (p1 - p0);
            int rounds = (cnt + 7) >> 3;
            float accA[4] = {0.f, 0.f, 0.f, 0.f}, accB[4] = {0.f, 0.f, 0.f, 0.f};
            int e = g;
            int idx = (g == 0) ? n : ((g < cnt) ? csr[p0 + g - 1] : -1);
            uint4 v;
            if (idx >= 0) v = *(const uint4*)(y32 + (long)idx * 32 + 4 * l);
            for (int r = 0; r < rounds; r++) {
                int ne = e + 8;
                int nidx = (ne < cnt) ? csr[p0 + ne - 1] : -1;
                uint4 vn;
                if (nidx >= 0) vn = *(const uint4*)(y32 + (long)nidx * 32 + 4 * l);
                if (idx >= 0) {
                    accA[0] += __uint_as_float(v.x << 16);
                    accB[0] += __uint_as_float(v.x & 0xffff0000u);
                    accA[1] += __uint_as_float(v.y << 16);
                    accB[1] += __uint_as_float(v.y & 0xffff0000u);
                    accA[2] += __uint_as_float(v.z << 16);
                    accB[2] += __uint_as_float(v.z & 0xffff0000u);
                    accA[3] += __uint_as_float(v.w << 16);
                    accB[3] += __uint_as_float(v.w & 0xffff0000u);
                }
                e = ne; idx = nidx; v = vn;
            }
#pragma unroll
            for (int m = 0; m < 4; m++) {
                accA[m] += __shfl_xor(accA[m], 8);
                accB[m] += __shfl_xor(accB[m], 8);
                accA[m] += __shfl_xor(accA[m], 16);
                accB[m] += __shfl_xor(accB[m], 16);
                accA[m] += __shfl_xor(accA[m], 32);
                accB[m] += __shfl_xor(accB[m], 32);
            }
            if (g == 0) {
                uint4 o;
                o.x = (uint_t)f2b(accA[0]) | ((uint_t)f2b(accB[0]) << 16);
                o.y = (uint_t)f2b(accA[1]) | ((uint_t)f2b(accB[1]) << 16);
                o.z = (uint_t)f2b(accA[2]) | ((uint_t)f2b(accB[2]) << 16);
                o.w = (uint_t)f2b(accA[3]) | ((uint_t)f2b(accB[3]) << 16);
                *(uint4*)&aggOut[(long)n * 32 + 4 * l] = o;
                st1[0] += accA[0]; st2[0] += accA[0] * accA[0];
                st1[1] += accB[0]; st2[1] += accB[0] * accB[0];
                st1[2] += accA[1]; st2[2] += accA[1] * accA[1];
                st1[3] += accB[1]; st2[3] += accB[1] * accB[1];
                st1[4] += accA[2]; st2[4] += accA[2] * accA[2];
                st1[5] += accB[2]; st2[5] += accB[2] * accB[2];
                st1[6] += accA[3]; st2[6] += accA[3] * accA[3];
                st1[7] += accB[3]; st2[7] += accB[3] * accB[3];
            }
        }
    }
    if (g == 0) {
#pragma unroll
        for (int m = 0; m < 8; m++) { l1[wv][8 * l + m] = st1[m]; l2[wv][8 * l + m] = st2[m]; }
    }
    __syncthreads();
    if (t < 64) {
        float S = l1[0][t] + l1[1][t] + l1[2][t] + l1[3][t];
        float S2 = l2[0][t] + l2[1][t] + l2[2][t] + l2[3][t];
        int slot = blockIdx.x & (NSLOT - 1);
        atomicAdd(&bn1p[slot * 128 + t], S);
        atomicAdd(&bn1p[slot * 128 + 64 + t], S2);
    }
}

// --- pooled[g] += relu(BN2(h2)) (sorted graph_ids) — last layer only --------
__global__ __launch_bounds__(256) void bn_pool(const uint_t* __restrict__ h2,
                                               const float* __restrict__ bn2p,
                                               const float* __restrict__ g2,
                                               const float* __restrict__ b2,
                                               const int* __restrict__ gid,
                                               float* __restrict__ pooled) {
    __shared__ float sc[64], sh[64];
    int t = threadIdx.x;
    if (t < 64) {
        float S = 0.f, S2 = 0.f;
        for (int s = 0; s < NSLOT; s++) { S += bn2p[s * 128 + t]; S2 += bn2p[s * 128 + 64 + t]; }
        float mean = S * (1.f / N_NODES);
        float var = S2 * (1.f / N_NODES) - mean * mean;
        float r = rsqrtf(var + BN_EPS);
        float scv = g2[t] * r;
        sc[t] = scv; sh[t] = b2[t] - mean * scv;
    }
    __syncthreads();
    int c = t & 31, rs = t >> 5;
    float sA = sc[2 * c], hA = sh[2 * c], sB = sc[2 * c + 1], hB = sh[2 * c + 1];
    long base = (long)blockIdx.x * 256;
    float pa = 0.f, pb2 = 0.f; int gc = -1;
    for (int i = 0; i < 32; i++) {
        long n = base + rs + 8 * i;
        if (n >= N_NODES) break;
        int g = gid[n];
        uint_t v = h2[n * 32 + c];
        float x0 = fmaxf(blo(v) * sA + hA, 0.f);
        float x1 = fmaxf(bhi(v) * sB + hB, 0.f);
        if (g != gc) {
            if (gc >= 0) {
                atomicAdd(&pooled[(long)gc * 64 + 2 * c], pa);
                atomicAdd(&pooled[(long)gc * 64 + 2 * c + 1], pb2);
            }
            gc = g; pa = 0.f; pb2 = 0.f;
        }
        pa += x0; pb2 += x1;
    }
    if (gc >= 0) {
        atomicAdd(&pooled[(long)gc * 64 + 2 * c], pa);
        atomicAdd(&pooled[(long)gc * 64 + 2 * c + 1], pb2);
    }
}

// --------- score = sum_l pooled_l @ pred_w_l + pred_b_l --------------------
__global__ __launch_bounds__(256) void score_kernel(const float* __restrict__ pooled,
                                                    const float* __restrict__ pw,
                                                    const float* __restrict__ pb,
                                                    float* __restrict__ out) {
    int idx = blockIdx.x * 256 + threadIdx.x;  // 16384 = 512*32
    int g = idx >> 5, o = idx & 31;
    float acc = 0.f;
    for (int l = 0; l < N_CONV; l++) {
        acc += pb[l * 32 + o];
        const float* pr = pooled + (long)l * N_GRAPHS * 64 + (long)g * 64;
        const float* wr = pw + l * 64 * 32;
        for (int k = 0; k < 64; k++) acc += pr[k] * wr[k * 32 + o];
    }
    out[idx] = acc;
}

extern "C" void kernel_launch(void* const* d_in, const int* in_sizes, int n_in,
                              void* d_out, int out_size, void* d_ws, size_t ws_size,
                              hipStream_t stream) {
    const float* h     = (const float*)d_in[0];
    const int*   src   = (const int*)d_in[1];
    const int*   dst   = (const int*)d_in[2];
    const int*   gid   = (const int*)d_in[3];
    const float* fc1w0 = (const float*)d_in[4];
    const float* fc1w  = (const float*)d_in[5];
    const float* fc2w  = (const float*)d_in[6];
    const float* bn1g  = (const float*)d_in[7];
    const float* bn1b  = (const float*)d_in[8];
    const float* bn2g  = (const float*)d_in[9];
    const float* bn2b  = (const float*)d_in[10];
    const float* pw    = (const float*)d_in[11];
    const float* pb    = (const float*)d_in[12];
    float* out = (float*)d_out;

    char* ws = (char*)d_ws;
    uint_t*   AGG16   = (uint_t*)  (ws);              // agg bf16 [N][64]: 12,800,000
    uint_t*   pairs   = (uint_t*)  (ws);              // packed pairs 6,400,000 (alias; dead before layer-0 aggregate)
    ushort_t* X16     = (ushort_t*)(ws + 25600000);   // h2 bf16 [N][64]: 12,800,000
    ushort_t* Y16     = (ushort_t*)(ws + 38400000);   // y bf16 [N][64]: 12,800,000
    float*    bnst    = (float*)   (ws + 51200000);   // 131,072
    float*    pooled  = (float*)   (ws + 51331072);   // 524,288
    int*   bucketCnt  = (int*)     (ws + 51855360);   // 2,048
    int*   bucketOffs = (int*)     (ws + 51857408);   // 2,052
    int*   bucketCur  = (int*)     (ws + 51859460);   // 2,048
    int*   offs       = (int*)     (ws + 51861508);   // 400,004
    int*   csr        = (int*)     (ws + 52261512);   // 6,400,000 (end 58,661,512)

    // zero: bnst + pooled + bucketCnt (contiguous: 51,200,000 .. 51,857,408)
    const int zwords = (51857408 - 51200000) / 4;     // 164,352
    zero_kernel<<<(zwords + 255) / 256, 256, 0, stream>>>((int*)bnst, zwords);

    bucket_count<<<(N_EDGES + 4095) / 4096, 256, 0, stream>>>(dst, bucketCnt);
    bucket_scan<<<1, 512, 0, stream>>>(bucketCnt, bucketOffs, bucketCur);
    binned_scatter<<<(N_EDGES + CHUNK - 1) / CHUNK, 256, 0, stream>>>(src, dst, bucketCur, pairs);
    csr_finalize<<<NBUSED, 256, 0, stream>>>(pairs, bucketOffs, offs, csr);

    for (int l = 0; l < N_CONV; l++) {
        float* bn1p = bnst + (long)l * 8192;
        float* bn2p = bn1p + 4096;
        if (l == 0) {
            gemm0<<<GEMM_BLOCKS, 256, 0, stream>>>(h, fc1w0, Y16);
        } else {
            float* bn2p_prev = bnst + (long)(l - 1) * 8192 + 4096;
            float* pl_prev = pooled + (long)(l - 1) * N_GRAPHS * 64;
            gemm_bn<false, true><<<GEMM_BLOCKS, 256, 0, stream>>>((const uint4*)X16,
                fc1w + (long)(l - 1) * 4096, bn2p_prev,
                bn2g + (l - 1) * 64, bn2b + (l - 1) * 64, Y16,
                (float*)nullptr, gid, pl_prev);
        }
        aggregate<<<AGG_BLOCKS, 256, 0, stream>>>((const uint_t*)Y16, offs, csr, AGG16, bn1p);
        gemm_bn<true, false><<<GEMM_BLOCKS, 256, 0, stream>>>((const uint4*)AGG16,
            fc2w + (long)l * 4096, bn1p, bn1g + l * 64, bn1b + l * 64, X16, bn2p,
            (const int*)nullptr, (float*)nullptr);
    }
    bn_pool<<<391, 256, 0, stream>>>((const uint_t*)X16,
        bnst + 3 * 8192 + 4096, bn2g + 3 * 64, bn2b + 3 * 64, gid,
        pooled + 3L * N_GRAPHS * 64);
    score_kernel<<<64, 256, 0, stream>>>(pooled, pw, pb, out);
}

// Round 11
// 405.699 us; speedup vs baseline: 2.2321x; 1.2550x over previous
//
#include <hip/hip_runtime.h>

#define N_NODES 100000
#define N_EDGES 1600000
#define N_GRAPHS 512
#define D_IN 128
#define D_H 64
#define D_OUT 32
#define N_CONV 4
#define BN_EPS 1e-5f
#define NSLOT 32

#define NB 512        // buckets
#define NPB 196       // nodes per bucket
#define NBUSED 511
#define CHUNK 8192    // edges per binned_scatter block
#define MAXE 4096     // max edges per bucket (mean 3136)
#define AGG_BLOCKS 2048
#define AGG_CHUNKS 3125

typedef unsigned short ushort_t;
typedef unsigned int uint_t;
typedef __attribute__((ext_vector_type(8))) short bf16x8;
typedef __attribute__((ext_vector_type(4))) float f32x4;
union U4B8 { uint4 u; bf16x8 v; };

__device__ inline float b2f(ushort_t u) {
    union { uint_t i; float f; } c; c.i = ((uint_t)u) << 16; return c.f;
}
__device__ inline ushort_t f2b(float f) {
    union { uint_t i; float f; } c; c.f = f;
    uint_t r = (c.i + 0x7fffu + ((c.i >> 16) & 1u)) >> 16;
    return (ushort_t)r;
}
__device__ inline float blo(uint_t v) { return b2f((ushort_t)(v & 0xffffu)); }
__device__ inline float bhi(uint_t v) { return b2f((ushort_t)(v >> 16)); }

// ---------------- utility: zero a region ------------------------------------
__global__ __launch_bounds__(256) void zero_kernel(int* __restrict__ p, int nwords) {
    int i = blockIdx.x * 256 + threadIdx.x;
    if (i < nwords) p[i] = 0;
}

// ---------------- CSR build: bucket histogram -------------------------------
__global__ __launch_bounds__(256) void bucket_count(const int* __restrict__ dst,
                                                    int* __restrict__ bucketCnt) {
    __shared__ int l[NB];
    int t = threadIdx.x;
    for (int i = t; i < NB; i += 256) l[i] = 0;
    __syncthreads();
    long base = (long)blockIdx.x * 4096;
    for (int i = t; i < 4096; i += 256) {
        long e = base + i;
        if (e < N_EDGES) atomicAdd(&l[(unsigned)dst[e] / NPB], 1);
    }
    __syncthreads();
    for (int i = t; i < NB; i += 256) if (l[i]) atomicAdd(&bucketCnt[i], l[i]);
}

// ---------------- bucket offsets scan ---------------------------------------
__global__ __launch_bounds__(512) void bucket_scan(const int* __restrict__ bucketCnt,
                                                   int* __restrict__ bucketOffs,
                                                   int* __restrict__ bucketCur) {
    __shared__ int s[512];
    int t = threadIdx.x;
    int v = bucketCnt[t];
    s[t] = v;
    __syncthreads();
    for (int off = 1; off < 512; off <<= 1) {
        int u = (t >= off) ? s[t - off] : 0;
        __syncthreads();
        s[t] += u;
        __syncthreads();
    }
    int excl = s[t] - v;
    bucketOffs[t] = excl;
    bucketCur[t] = excl;
    if (t == 511) bucketOffs[512] = s[511];
}

// ------- binned scatter: LDS counting-sort by bucket; packed 26-bit pairs ----
__global__ __launch_bounds__(256) void binned_scatter(const int* __restrict__ src,
                                                      const int* __restrict__ dst,
                                                      int* __restrict__ bucketCur,
                                                      uint_t* __restrict__ pairs) {
    __shared__ uint_t sortedp[CHUNK];        // 32 KB
    __shared__ ushort_t sbkt[CHUNK];         // 16 KB
    __shared__ int lcnt[NB], loffs[NB], lcur[NB], gbase[NB];
    __shared__ int ps[256];
    int t = threadIdx.x;
    long e0 = (long)blockIdx.x * CHUNK;
    int nvalid = (int)min((long)CHUNK, (long)N_EDGES - e0);
    for (int i = t; i < NB; i += 256) lcnt[i] = 0;
    __syncthreads();
    for (int i = t; i < nvalid; i += 256)
        atomicAdd(&lcnt[(unsigned)dst[e0 + i] / NPB], 1);
    __syncthreads();
    int a0 = lcnt[2 * t], a1 = lcnt[2 * t + 1];
    ps[t] = a0 + a1;
    __syncthreads();
    for (int off = 1; off < 256; off <<= 1) {
        int u = (t >= off) ? ps[t - off] : 0;
        __syncthreads();
        ps[t] += u;
        __syncthreads();
    }
    int ex = ps[t] - (a0 + a1);
    loffs[2 * t] = ex; loffs[2 * t + 1] = ex + a0;
    lcur[2 * t] = ex;  lcur[2 * t + 1] = ex + a0;
    __syncthreads();
    for (int i = t; i < NB; i += 256) {
        int c = lcnt[i];
        gbase[i] = c ? atomicAdd(&bucketCur[i], c) : 0;
    }
    for (int i = t; i < nvalid; i += 256) {
        int d = dst[e0 + i];
        int b = (unsigned)d / NPB;
        int pos = atomicAdd(&lcur[b], 1);
        sortedp[pos] = ((uint_t)src[e0 + i] << 9) | (uint_t)(d - b * NPB);
        sbkt[pos] = (ushort_t)b;
    }
    __syncthreads();
    for (int i = t; i < nvalid; i += 256) {
        int b = sbkt[i];
        long gpos = (long)gbase[b] + (i - loffs[b]);
        pairs[gpos] = sortedp[i];
    }
}

// ---------------- per-bucket CSR finalize (packed pairs) --------------------
__global__ __launch_bounds__(256) void csr_finalize(const uint_t* __restrict__ pairs,
                                                    const int* __restrict__ bucketOffs,
                                                    int* __restrict__ offs,
                                                    int* __restrict__ csr) {
    __shared__ uint_t lp[MAXE];    // 16 KB
    __shared__ int lsrc[MAXE];     // 16 KB
    __shared__ int lcnt[NPB], lcur[NPB];
    __shared__ int ls[256];
    int b = blockIdx.x, t = threadIdx.x;
    int e0 = bucketOffs[b], e1 = bucketOffs[b + 1];
    int ne = e1 - e0;
    int n0 = b * NPB;
    int nn = min(NPB, N_NODES - n0);
    for (int i = t; i < ne; i += 256) lp[i] = pairs[e0 + i];
    for (int i = t; i < nn; i += 256) lcnt[i] = 0;
    __syncthreads();
    for (int i = t; i < ne; i += 256) atomicAdd(&lcnt[lp[i] & 511u], 1);
    __syncthreads();
    int v = (t < nn) ? lcnt[t] : 0;
    ls[t] = v;
    __syncthreads();
    for (int off = 1; off < 256; off <<= 1) {
        int u = (t >= off) ? ls[t - off] : 0;
        __syncthreads();
        ls[t] += u;
        __syncthreads();
    }
    if (t < nn) { lcur[t] = ls[t] - v; offs[n0 + t] = e0 + ls[t] - v; }
    if (t == 0 && b == NBUSED - 1) offs[N_NODES] = e1;
    __syncthreads();
    for (int i = t; i < ne; i += 256) {
        uint_t p = lp[i];
        int pos = atomicAdd(&lcur[p & 511u], 1);
        lsrc[pos] = (int)(p >> 9);
    }
    __syncthreads();
    for (int i = t; i < ne; i += 256) csr[e0 + i] = lsrc[i];
}

// --------- MFMA GEMM layer0: y16[N][64] = bf16(h f32 [N][128]) @ bf16(w) ----
#define SLABS 4
#define GEMM_BLOCKS 391
__global__ __launch_bounds__(256) void gemm0(const float* __restrict__ in,
                                             const float* __restrict__ w,
                                             ushort_t* __restrict__ y16) {
    __shared__ uint4 Bl[4][4][64];   // 16 KB
    int t = threadIdx.x;
    for (int idx = t; idx < 4 * 4 * 64; idx += 256) {
        int l = idx & 63, nt = (idx >> 6) & 3, kk = idx >> 8;
        int k0 = kk * 32 + ((l >> 4) << 3), c = nt * 16 + (l & 15);
        uint4 o;
        o.x = (uint_t)f2b(w[(k0 + 0) * 64 + c]) | ((uint_t)f2b(w[(k0 + 1) * 64 + c]) << 16);
        o.y = (uint_t)f2b(w[(k0 + 2) * 64 + c]) | ((uint_t)f2b(w[(k0 + 3) * 64 + c]) << 16);
        o.z = (uint_t)f2b(w[(k0 + 4) * 64 + c]) | ((uint_t)f2b(w[(k0 + 5) * 64 + c]) << 16);
        o.w = (uint_t)f2b(w[(k0 + 6) * 64 + c]) | ((uint_t)f2b(w[(k0 + 7) * 64 + c]) << 16);
        Bl[kk][nt][l] = o;
    }
    __syncthreads();
    int wv = t >> 6, lane = t & 63, lq = lane >> 4, lr = lane & 15;
    bf16x8 B[4][4];
#pragma unroll
    for (int kk = 0; kk < 4; kk++)
#pragma unroll
        for (int nt = 0; nt < 4; nt++) { U4B8 cv; cv.u = Bl[kk][nt][lane]; B[kk][nt] = cv.v; }
    for (int s = 0; s < SLABS; s++) {
        long rb = ((long)blockIdx.x * SLABS + s) * 64 + wv * 16;
        long n = rb + lr;
        const float* rp = in + (n < N_NODES ? n : 0) * 128;
        f32x4 zero = {0.f, 0.f, 0.f, 0.f};
        f32x4 acc[4] = {zero, zero, zero, zero};
#pragma unroll
        for (int kk = 0; kk < 4; kk++) {
            float4 u = *(const float4*)(rp + kk * 32 + lq * 8);
            float4 v = *(const float4*)(rp + kk * 32 + lq * 8 + 4);
            bf16x8 a;
            a[0] = (short)f2b(u.x); a[1] = (short)f2b(u.y);
            a[2] = (short)f2b(u.z); a[3] = (short)f2b(u.w);
            a[4] = (short)f2b(v.x); a[5] = (short)f2b(v.y);
            a[6] = (short)f2b(v.z); a[7] = (short)f2b(v.w);
#pragma unroll
            for (int nt = 0; nt < 4; nt++)
                acc[nt] = __builtin_amdgcn_mfma_f32_16x16x32_bf16(a, B[kk][nt], acc[nt], 0, 0, 0);
        }
#pragma unroll
        for (int nt = 0; nt < 4; nt++)
#pragma unroll
            for (int j = 0; j < 4; j++) {
                long rr = rb + lq * 4 + j;
                if (rr < N_NODES) y16[rr * 64 + nt * 16 + lr] = f2b(acc[nt][j]);
            }
    }
}

// --- MFMA GEMM + fused input BN/relu: out = relu(BN(in_bf16)) @ w -----------
// OSTAT: accumulate output column stats (fc2 -> bn2p)
template <bool OSTAT>
__global__ __launch_bounds__(256) void gemm_bn(const uint4* __restrict__ in,
                                               const float* __restrict__ w,
                                               const float* __restrict__ bnip,
                                               const float* __restrict__ gi,
                                               const float* __restrict__ bi,
                                               ushort_t* __restrict__ outY,
                                               float* __restrict__ ostat) {
    __shared__ uint4 Bl[2][4][64];   // 8 KB
    __shared__ float sc[64], sh[64];
    __shared__ float red1[4][64], red2[4][64];
    int t = threadIdx.x;
    if (t < 64) {
        float S = 0.f, S2 = 0.f;
        for (int s = 0; s < NSLOT; s++) { S += bnip[s * 128 + t]; S2 += bnip[s * 128 + 64 + t]; }
        float mean = S * (1.f / N_NODES);
        float var = S2 * (1.f / N_NODES) - mean * mean;
        float r = rsqrtf(var + BN_EPS);
        float scv = gi[t] * r;
        sc[t] = scv; sh[t] = bi[t] - mean * scv;
    }
    for (int idx = t; idx < 2 * 4 * 64; idx += 256) {
        int l = idx & 63, nt = (idx >> 6) & 3, kk = idx >> 8;
        int k0 = kk * 32 + ((l >> 4) << 3), c = nt * 16 + (l & 15);
        uint4 o;
        o.x = (uint_t)f2b(w[(k0 + 0) * 64 + c]) | ((uint_t)f2b(w[(k0 + 1) * 64 + c]) << 16);
        o.y = (uint_t)f2b(w[(k0 + 2) * 64 + c]) | ((uint_t)f2b(w[(k0 + 3) * 64 + c]) << 16);
        o.z = (uint_t)f2b(w[(k0 + 4) * 64 + c]) | ((uint_t)f2b(w[(k0 + 5) * 64 + c]) << 16);
        o.w = (uint_t)f2b(w[(k0 + 6) * 64 + c]) | ((uint_t)f2b(w[(k0 + 7) * 64 + c]) << 16);
        Bl[kk][nt][l] = o;
    }
    __syncthreads();
    int wv = t >> 6, lane = t & 63, lq = lane >> 4, lr = lane & 15;
    bf16x8 B[2][4];
#pragma unroll
    for (int kk = 0; kk < 2; kk++)
#pragma unroll
        for (int nt = 0; nt < 4; nt++) { U4B8 cv; cv.u = Bl[kk][nt][lane]; B[kk][nt] = cv.v; }
    float s1[4] = {0.f, 0.f, 0.f, 0.f}, s2[4] = {0.f, 0.f, 0.f, 0.f};
    for (int s = 0; s < SLABS; s++) {
        long rb = ((long)blockIdx.x * SLABS + s) * 64 + wv * 16;
        long n = rb + lr;
        bool ok = n < N_NODES;
        const uint4* rp = in + (ok ? n : 0) * 8;
        f32x4 zero = {0.f, 0.f, 0.f, 0.f};
        f32x4 acc[4] = {zero, zero, zero, zero};
#pragma unroll
        for (int kk = 0; kk < 2; kk++) {
            bf16x8 a;
            if (ok) {
                uint4 v = rp[kk * 4 + lq];
                int k0 = kk * 32 + lq * 8;
                float x0 = fmaxf(blo(v.x) * sc[k0 + 0] + sh[k0 + 0], 0.f);
                float x1 = fmaxf(bhi(v.x) * sc[k0 + 1] + sh[k0 + 1], 0.f);
                float x2 = fmaxf(blo(v.y) * sc[k0 + 2] + sh[k0 + 2], 0.f);
                float x3 = fmaxf(bhi(v.y) * sc[k0 + 3] + sh[k0 + 3], 0.f);
                float x4 = fmaxf(blo(v.z) * sc[k0 + 4] + sh[k0 + 4], 0.f);
                float x5 = fmaxf(bhi(v.z) * sc[k0 + 5] + sh[k0 + 5], 0.f);
                float x6 = fmaxf(blo(v.w) * sc[k0 + 6] + sh[k0 + 6], 0.f);
                float x7 = fmaxf(bhi(v.w) * sc[k0 + 7] + sh[k0 + 7], 0.f);
                a[0] = (short)f2b(x0); a[1] = (short)f2b(x1);
                a[2] = (short)f2b(x2); a[3] = (short)f2b(x3);
                a[4] = (short)f2b(x4); a[5] = (short)f2b(x5);
                a[6] = (short)f2b(x6); a[7] = (short)f2b(x7);
            } else {
#pragma unroll
                for (int j = 0; j < 8; j++) a[j] = 0;
            }
#pragma unroll
            for (int nt = 0; nt < 4; nt++)
                acc[nt] = __builtin_amdgcn_mfma_f32_16x16x32_bf16(a, B[kk][nt], acc[nt], 0, 0, 0);
        }
#pragma unroll
        for (int nt = 0; nt < 4; nt++)
#pragma unroll
            for (int j = 0; j < 4; j++) {
                long rr = rb + lq * 4 + j;
                float val = acc[nt][j];
                if (rr < N_NODES) outY[rr * 64 + nt * 16 + lr] = f2b(val);
                if (OSTAT) { s1[nt] += val; s2[nt] += val * val; }
            }
    }
    if (OSTAT) {
#pragma unroll
        for (int nt = 0; nt < 4; nt++) {
            s1[nt] += __shfl_xor(s1[nt], 16); s1[nt] += __shfl_xor(s1[nt], 32);
            s2[nt] += __shfl_xor(s2[nt], 16); s2[nt] += __shfl_xor(s2[nt], 32);
        }
        if (lq == 0) {
#pragma unroll
            for (int nt = 0; nt < 4; nt++) {
                red1[wv][nt * 16 + lr] = s1[nt];
                red2[wv][nt * 16 + lr] = s2[nt];
            }
        }
        __syncthreads();
        if (t < 64) {
            float S = red1[0][t] + red1[1][t] + red1[2][t] + red1[3][t];
            float S2 = red2[0][t] + red2[1][t] + red2[2][t] + red2[3][t];
            int slot = blockIdx.x & (NSLOT - 1);
            atomicAdd(&ostat[slot * 128 + t], S);
            atomicAdd(&ostat[slot * 128 + 64 + t], S2);
        }
    }
}

// ------- aggregation: agg16 = y16 + sum_nb y16[nb] + BN1 stats --------------
// persistent grid (2048 blocks); 8 edge-slots x 8 col-chunks; value prefetch
__global__ __launch_bounds__(256) void aggregate(const uint_t* __restrict__ y32,
                                                 const int* __restrict__ offs,
                                                 const int* __restrict__ csr,
                                                 uint_t* __restrict__ aggOut,
                                                 float* __restrict__ bn1p) {
    int t = threadIdx.x;
    int wv = t >> 6, lane = t & 63;
    int g = lane >> 3, l = lane & 7;
    __shared__ float l1[4][64], l2[4][64];
    float st1[8], st2[8];
#pragma unroll
    for (int m = 0; m < 8; m++) { st1[m] = 0.f; st2[m] = 0.f; }
    for (int chunk = blockIdx.x; chunk < AGG_CHUNKS; chunk += AGG_BLOCKS) {
        int nb_base = chunk * 32 + wv * 8;
        for (int j = 0; j < 8; j++) {
            int n = nb_base + j;
            int p0 = offs[n], p1 = offs[n + 1];
            int cnt = 1 + (p1 - p0);
            int rounds = (cnt + 7) >> 3;
            float accA[4] = {0.f, 0.f, 0.f, 0.f}, accB[4] = {0.f, 0.f, 0.f, 0.f};
            int e = g;
            int idx = (g == 0) ? n : ((g < cnt) ? csr[p0 + g - 1] : -1);
            uint4 v;
            if (idx >= 0) v = *(const uint4*)(y32 + (long)idx * 32 + 4 * l);
            for (int r = 0; r < rounds; r++) {
                int ne = e + 8;
                int nidx = (ne < cnt) ? csr[p0 + ne - 1] : -1;
                uint4 vn;
                if (nidx >= 0) vn = *(const uint4*)(y32 + (long)nidx * 32 + 4 * l);
                if (idx >= 0) {
                    accA[0] += __uint_as_float(v.x << 16);
                    accB[0] += __uint_as_float(v.x & 0xffff0000u);
                    accA[1] += __uint_as_float(v.y << 16);
                    accB[1] += __uint_as_float(v.y & 0xffff0000u);
                    accA[2] += __uint_as_float(v.z << 16);
                    accB[2] += __uint_as_float(v.z & 0xffff0000u);
                    accA[3] += __uint_as_float(v.w << 16);
                    accB[3] += __uint_as_float(v.w & 0xffff0000u);
                }
                e = ne; idx = nidx; v = vn;
            }
#pragma unroll
            for (int m = 0; m < 4; m++) {
                accA[m] += __shfl_xor(accA[m], 8);
                accB[m] += __shfl_xor(accB[m], 8);
                accA[m] += __shfl_xor(accA[m], 16);
                accB[m] += __shfl_xor(accB[m], 16);
                accA[m] += __shfl_xor(accA[m], 32);
                accB[m] += __shfl_xor(accB[m], 32);
            }
            if (g == 0) {
                uint4 o;
                o.x = (uint_t)f2b(accA[0]) | ((uint_t)f2b(accB[0]) << 16);
                o.y = (uint_t)f2b(accA[1]) | ((uint_t)f2b(accB[1]) << 16);
                o.z = (uint_t)f2b(accA[2]) | ((uint_t)f2b(accB[2]) << 16);
                o.w = (uint_t)f2b(accA[3]) | ((uint_t)f2b(accB[3]) << 16);
                *(uint4*)&aggOut[(long)n * 32 + 4 * l] = o;
                st1[0] += accA[0]; st2[0] += accA[0] * accA[0];
                st1[1] += accB[0]; st2[1] += accB[0] * accB[0];
                st1[2] += accA[1]; st2[2] += accA[1] * accA[1];
                st1[3] += accB[1]; st2[3] += accB[1] * accB[1];
                st1[4] += accA[2]; st2[4] += accA[2] * accA[2];
                st1[5] += accB[2]; st2[5] += accB[2] * accB[2];
                st1[6] += accA[3]; st2[6] += accA[3] * accA[3];
                st1[7] += accB[3]; st2[7] += accB[3] * accB[3];
            }
        }
    }
    if (g == 0) {
#pragma unroll
        for (int m = 0; m < 8; m++) { l1[wv][8 * l + m] = st1[m]; l2[wv][8 * l + m] = st2[m]; }
    }
    __syncthreads();
    if (t < 64) {
        float S = l1[0][t] + l1[1][t] + l1[2][t] + l1[3][t];
        float S2 = l2[0][t] + l2[1][t] + l2[2][t] + l2[3][t];
        int slot = blockIdx.x & (NSLOT - 1);
        atomicAdd(&bn1p[slot * 128 + t], S);
        atomicAdd(&bn1p[slot * 128 + 64 + t], S2);
    }
}

// --- pooled[g] += relu(BN2(h2)) (sorted graph_ids) --------------------------
__global__ __launch_bounds__(256) void bn_pool(const uint_t* __restrict__ h2,
                                               const float* __restrict__ bn2p,
                                               const float* __restrict__ g2,
                                               const float* __restrict__ b2,
                                               const int* __restrict__ gid,
                                               float* __restrict__ pooled) {
    __shared__ float sc[64], sh[64];
    int t = threadIdx.x;
    if (t < 64) {
        float S = 0.f, S2 = 0.f;
        for (int s = 0; s < NSLOT; s++) { S += bn2p[s * 128 + t]; S2 += bn2p[s * 128 + 64 + t]; }
        float mean = S * (1.f / N_NODES);
        float var = S2 * (1.f / N_NODES) - mean * mean;
        float r = rsqrtf(var + BN_EPS);
        float scv = g2[t] * r;
        sc[t] = scv; sh[t] = b2[t] - mean * scv;
    }
    __syncthreads();
    int c = t & 31, rs = t >> 5;
    float sA = sc[2 * c], hA = sh[2 * c], sB = sc[2 * c + 1], hB = sh[2 * c + 1];
    long base = (long)blockIdx.x * 256;
    float pa = 0.f, pb2 = 0.f; int gc = -1;
    for (int i = 0; i < 32; i++) {
        long n = base + rs + 8 * i;
        if (n >= N_NODES) break;
        int g = gid[n];
        uint_t v = h2[n * 32 + c];
        float x0 = fmaxf(blo(v) * sA + hA, 0.f);
        float x1 = fmaxf(bhi(v) * sB + hB, 0.f);
        if (g != gc) {
            if (gc >= 0) {
                atomicAdd(&pooled[(long)gc * 64 + 2 * c], pa);
                atomicAdd(&pooled[(long)gc * 64 + 2 * c + 1], pb2);
            }
            gc = g; pa = 0.f; pb2 = 0.f;
        }
        pa += x0; pb2 += x1;
    }
    if (gc >= 0) {
        atomicAdd(&pooled[(long)gc * 64 + 2 * c], pa);
        atomicAdd(&pooled[(long)gc * 64 + 2 * c + 1], pb2);
    }
}

// --------- score = sum_l pooled_l @ pred_w_l + pred_b_l --------------------
__global__ __launch_bounds__(256) void score_kernel(const float* __restrict__ pooled,
                                                    const float* __restrict__ pw,
                                                    const float* __restrict__ pb,
                                                    float* __restrict__ out) {
    int idx = blockIdx.x * 256 + threadIdx.x;  // 16384 = 512*32
    int g = idx >> 5, o = idx & 31;
    float acc = 0.f;
    for (int l = 0; l < N_CONV; l++) {
        acc += pb[l * 32 + o];
        const float* pr = pooled + (long)l * N_GRAPHS * 64 + (long)g * 64;
        const float* wr = pw + l * 64 * 32;
        for (int k = 0; k < 64; k++) acc += pr[k] * wr[k * 32 + o];
    }
    out[idx] = acc;
}

extern "C" void kernel_launch(void* const* d_in, const int* in_sizes, int n_in,
                              void* d_out, int out_size, void* d_ws, size_t ws_size,
                              hipStream_t stream) {
    const float* h     = (const float*)d_in[0];
    const int*   src   = (const int*)d_in[1];
    const int*   dst   = (const int*)d_in[2];
    const int*   gid   = (const int*)d_in[3];
    const float* fc1w0 = (const float*)d_in[4];
    const float* fc1w  = (const float*)d_in[5];
    const float* fc2w  = (const float*)d_in[6];
    const float* bn1g  = (const float*)d_in[7];
    const float* bn1b  = (const float*)d_in[8];
    const float* bn2g  = (const float*)d_in[9];
    const float* bn2b  = (const float*)d_in[10];
    const float* pw    = (const float*)d_in[11];
    const float* pb    = (const float*)d_in[12];
    float* out = (float*)d_out;

    char* ws = (char*)d_ws;
    uint_t*   AGG16   = (uint_t*)  (ws);              // agg bf16 [N][64]: 12,800,000
    uint_t*   pairs   = (uint_t*)  (ws);              // packed pairs 6,400,000 (alias; dead before layer-0 aggregate)
    ushort_t* X16     = (ushort_t*)(ws + 25600000);   // h2 bf16 [N][64]: 12,800,000
    ushort_t* Y16     = (ushort_t*)(ws + 38400000);   // y bf16 [N][64]: 12,800,000
    float*    bnst    = (float*)   (ws + 51200000);   // 131,072
    float*    pooled  = (float*)   (ws + 51331072);   // 524,288
    int*   bucketCnt  = (int*)     (ws + 51855360);   // 2,048
    int*   bucketOffs = (int*)     (ws + 51857408);   // 2,052
    int*   bucketCur  = (int*)     (ws + 51859460);   // 2,048
    int*   offs       = (int*)     (ws + 51861508);   // 400,004
    int*   csr        = (int*)     (ws + 52261512);   // 6,400,000 (end 58,661,512)

    // zero: bnst + pooled + bucketCnt (contiguous: 51,200,000 .. 51,857,408)
    const int zwords = (51857408 - 51200000) / 4;     // 164,352
    zero_kernel<<<(zwords + 255) / 256, 256, 0, stream>>>((int*)bnst, zwords);

    bucket_count<<<(N_EDGES + 4095) / 4096, 256, 0, stream>>>(dst, bucketCnt);
    bucket_scan<<<1, 512, 0, stream>>>(bucketCnt, bucketOffs, bucketCur);
    binned_scatter<<<(N_EDGES + CHUNK - 1) / CHUNK, 256, 0, stream>>>(src, dst, bucketCur, pairs);
    csr_finalize<<<NBUSED, 256, 0, stream>>>(pairs, bucketOffs, offs, csr);

    for (int l = 0; l < N_CONV; l++) {
        float* bn1p = bnst + (long)l * 8192;
        float* bn2p = bn1p + 4096;
        float* pl = pooled + (long)l * N_GRAPHS * 64;
        if (l == 0) {
            gemm0<<<GEMM_BLOCKS, 256, 0, stream>>>(h, fc1w0, Y16);
        } else {
            float* bn2p_prev = bnst + (long)(l - 1) * 8192 + 4096;
            gemm_bn<false><<<GEMM_BLOCKS, 256, 0, stream>>>((const uint4*)X16,
                fc1w + (long)(l - 1) * 4096, bn2p_prev,
                bn2g + (l - 1) * 64, bn2b + (l - 1) * 64, Y16, (float*)nullptr);
        }
        aggregate<<<AGG_BLOCKS, 256, 0, stream>>>((const uint_t*)Y16, offs, csr, AGG16, bn1p);
        gemm_bn<true><<<GEMM_BLOCKS, 256, 0, stream>>>((const uint4*)AGG16,
            fc2w + (long)l * 4096, bn1p, bn1g + l * 64, bn1b + l * 64, X16, bn2p);
        bn_pool<<<391, 256, 0, stream>>>((const uint_t*)X16, bn2p, bn2g + l * 64,
                                         bn2b + l * 64, gid, pl);
    }
    score_kernel<<<64, 256, 0, stream>>>(pooled, pw, pb, out);
}